// Round 1
// baseline (811.976 us; speedup 1.0000x reference)
//
#include <hip/hip_runtime.h>

// ---------------------------------------------------------------------------
// AttentionRelativeBias: B=128, S=256, D=768, H=12, DH=64, window 8x8 (=64 tok)
// Pipeline: 3x proj GEMM (fp32->bf16 MFMA) -> attention -> out proj GEMM
// ---------------------------------------------------------------------------

typedef __bf16 bf16;
typedef __bf16 bf16x4 __attribute__((ext_vector_type(4)));
typedef __bf16 bf16x8 __attribute__((ext_vector_type(8)));
typedef float  f32x4  __attribute__((ext_vector_type(4)));

#define MFMA_BF16(a, b, c) __builtin_amdgcn_mfma_f32_16x16x32_bf16((a), (b), (c), 0, 0, 0)

// GEMM: Y[M=32768, N=768] = X[M,768] @ W^T (W is [out,in] row-major) + bias
// MODE 0: store bf16 heads-split [B,H,S,DH]   (Q/K/V projections)
// MODE 1: store fp32 [M, 768]                  (output projection)
template <typename InT, int MODE>
__global__ __launch_bounds__(256)
void gemm_proj(const InT* __restrict__ X, const float* __restrict__ Wt,
               const float* __restrict__ bias, bf16* __restrict__ outb,
               float* __restrict__ outf)
{
    constexpr int K = 768;
    constexpr int BK = 64;
    constexpr int LDA = 72;  // bf16 elems per LDS row (64 + 8 pad; 144B = 9*16B)
    __shared__ bf16 As[128 * LDA];
    __shared__ bf16 Bs[128 * LDA];

    const int tid  = threadIdx.x;
    const int m0   = blockIdx.x * 128;
    const int n0   = blockIdx.y * 128;
    const int w    = tid >> 6;
    const int lane = tid & 63;
    const int quad = lane >> 4;
    const int l15  = lane & 15;
    const int wr   = (w >> 1) * 64;  // wave row offset in tile
    const int wc   = (w & 1) * 64;   // wave col offset in tile

    f32x4 acc[4][4] = {};

    for (int kt = 0; kt < K / BK; ++kt) {
        const int k0 = kt * BK;
        __syncthreads();
        // ---- stage X tile (128 x 64) ----
        if constexpr (sizeof(InT) == 4) {
            #pragma unroll
            for (int i = 0; i < 8; ++i) {
                int idx = i * 256 + tid;      // 0..2047
                int row = idx >> 4;
                int c4  = idx & 15;
                f32x4 xv = *(const f32x4*)((const float*)X + (size_t)(m0 + row) * K + k0 + c4 * 4);
                bf16x4 bv;
                bv[0] = (bf16)xv[0]; bv[1] = (bf16)xv[1];
                bv[2] = (bf16)xv[2]; bv[3] = (bf16)xv[3];
                *(bf16x4*)&As[row * LDA + c4 * 4] = bv;
            }
        } else {
            #pragma unroll
            for (int i = 0; i < 4; ++i) {
                int idx = i * 256 + tid;      // 0..1023
                int row = idx >> 3;
                int c8  = idx & 7;
                *(bf16x8*)&As[row * LDA + c8 * 8] =
                    *(const bf16x8*)((const bf16*)X + (size_t)(m0 + row) * K + k0 + c8 * 8);
            }
        }
        // ---- stage W tile (128 x 64), always fp32 ----
        #pragma unroll
        for (int i = 0; i < 8; ++i) {
            int idx = i * 256 + tid;
            int row = idx >> 4;
            int c4  = idx & 15;
            f32x4 wv = *(const f32x4*)(Wt + (size_t)(n0 + row) * K + k0 + c4 * 4);
            bf16x4 bv;
            bv[0] = (bf16)wv[0]; bv[1] = (bf16)wv[1];
            bv[2] = (bf16)wv[2]; bv[3] = (bf16)wv[3];
            *(bf16x4*)&Bs[row * LDA + c4 * 4] = bv;
        }
        __syncthreads();
        // ---- MFMA: 2 k-chunks of 32 ----
        #pragma unroll
        for (int kk = 0; kk < 2; ++kk) {
            bf16x8 af[4], bfr[4];
            #pragma unroll
            for (int mt = 0; mt < 4; ++mt)
                af[mt] = *(const bf16x8*)&As[(wr + mt * 16 + l15) * LDA + kk * 32 + quad * 8];
            #pragma unroll
            for (int nt = 0; nt < 4; ++nt)
                bfr[nt] = *(const bf16x8*)&Bs[(wc + nt * 16 + l15) * LDA + kk * 32 + quad * 8];
            #pragma unroll
            for (int mt = 0; mt < 4; ++mt)
                #pragma unroll
                for (int nt = 0; nt < 4; ++nt)
                    acc[mt][nt] = MFMA_BF16(af[mt], bfr[nt], acc[mt][nt]);
        }
    }

    // ---- epilogue: C layout col=lane&15, row=quad*4+reg ----
    #pragma unroll
    for (int mt = 0; mt < 4; ++mt) {
        #pragma unroll
        for (int nt = 0; nt < 4; ++nt) {
            int gn = n0 + wc + nt * 16 + l15;
            float bv = bias[gn];
            #pragma unroll
            for (int r = 0; r < 4; ++r) {
                int gm = m0 + wr + mt * 16 + quad * 4 + r;
                float val = acc[mt][nt][r] + bv;
                if constexpr (MODE == 0) {
                    int b = gm >> 8, s = gm & 255;
                    int h = gn >> 6, d = gn & 63;
                    outb[(((size_t)(b * 12 + h) << 8) + s) * 64 + d] = (bf16)val;
                } else {
                    outf[(size_t)gm * 768 + gn] = val;
                }
            }
        }
    }
}

// Attention: one block per (q-tile of 64, h, b). 4 waves, wave w owns q rows
// [w*16, w*16+16). Scores for full 256 keys live in registers (16 x f32x4).
__global__ __launch_bounds__(256)
void attn_kernel(const bf16* __restrict__ qh, const bf16* __restrict__ kh,
                 const bf16* __restrict__ vh, const float* __restrict__ table,
                 bf16* __restrict__ ctx)
{
    constexpr int LD = 72;               // padded bf16 row stride
    __shared__ bf16  Qs[64 * LD];        // 9216 B
    __shared__ bf16  Ks[64 * LD];        // 9216 B (one 64-key chunk)
    __shared__ bf16  Vt[64 * LD];        // 9216 B (transposed V chunk: [d][j])
    __shared__ bf16  Ps[4 * 16 * LD];    // 9216 B (per-wave P chunk, A-layout)
    __shared__ float Bsh[64 * 68];       // 17408 B (bias tile [i%64][j%64])

    const int tid  = threadIdx.x;
    const int qt   = blockIdx.x;   // 0..3
    const int h    = blockIdx.y;   // 0..11
    const int b    = blockIdx.z;   // 0..127
    const int w    = tid >> 6;
    const int lane = tid & 63;
    const int quad = lane >> 4;
    const int l15  = lane & 15;

    const size_t bh = (size_t)(b * 12 + h) * 256 * 64;
    const bf16* Qg = qh + bh + (size_t)qt * 64 * 64;
    const bf16* Kg = kh + bh;
    const bf16* Vg = vh + bh;

    // ---- load Q tile (64x64) ----
    {
        int row = tid >> 2, c0 = (tid & 3) * 16;
        *(bf16x8*)&Qs[row * LD + c0]     = *(const bf16x8*)(Qg + row * 64 + c0);
        *(bf16x8*)&Qs[row * LD + c0 + 8] = *(const bf16x8*)(Qg + row * 64 + c0 + 8);
    }
    // ---- build 64x64 bias tile for this head ----
    {
        int i = tid >> 2, j0 = (tid & 3) * 16;
        int ai = i >> 3, aj = i & 7;
        #pragma unroll
        for (int jj = 0; jj < 16; ++jj) {
            int j = j0 + jj;
            int idx = (ai - (j >> 3) + 7) * 15 + (aj - (j & 7) + 7);
            Bsh[i * 68 + j] = table[idx * 12 + h];
        }
    }

    // ---- QK^T over 4 key chunks of 64 ----
    f32x4 sacc[16] = {};
    bf16x8 qf0, qf1;
    for (int c = 0; c < 4; ++c) {
        __syncthreads();
        {
            int row = tid >> 2, c0 = (tid & 3) * 16;
            const bf16* src = Kg + (size_t)(c * 64 + row) * 64 + c0;
            *(bf16x8*)&Ks[row * LD + c0]     = *(const bf16x8*)(src);
            *(bf16x8*)&Ks[row * LD + c0 + 8] = *(const bf16x8*)(src + 8);
        }
        __syncthreads();
        if (c == 0) {
            qf0 = *(const bf16x8*)&Qs[(w * 16 + l15) * LD + quad * 8];
            qf1 = *(const bf16x8*)&Qs[(w * 16 + l15) * LD + 32 + quad * 8];
        }
        #pragma unroll
        for (int jtl = 0; jtl < 4; ++jtl) {
            bf16x8 kf0 = *(const bf16x8*)&Ks[(jtl * 16 + l15) * LD + quad * 8];
            bf16x8 kf1 = *(const bf16x8*)&Ks[(jtl * 16 + l15) * LD + 32 + quad * 8];
            sacc[c * 4 + jtl] = MFMA_BF16(qf0, kf0, sacc[c * 4 + jtl]);
            sacc[c * 4 + jtl] = MFMA_BF16(qf1, kf1, sacc[c * 4 + jtl]);
        }
    }

    // ---- softmax (rows live across 16 lanes of each quad) ----
    const int browbase = w * 16 + quad * 4;  // i%64 base for this lane's rows
    float p[16][4];
    #pragma unroll
    for (int jt = 0; jt < 16; ++jt) {
        int jcol = ((jt * 16) & 63) + l15;
        #pragma unroll
        for (int r = 0; r < 4; ++r)
            p[jt][r] = sacc[jt][r] * 0.125f + Bsh[(browbase + r) * 68 + jcol];
    }
    float invl[4];
    #pragma unroll
    for (int r = 0; r < 4; ++r) {
        float m = p[0][r];
        #pragma unroll
        for (int jt = 1; jt < 16; ++jt) m = fmaxf(m, p[jt][r]);
        #pragma unroll
        for (int off = 1; off < 16; off <<= 1)
            m = fmaxf(m, __shfl_xor(m, off, 64));
        float s = 0.f;
        #pragma unroll
        for (int jt = 0; jt < 16; ++jt) {
            p[jt][r] = __expf(p[jt][r] - m);
            s += p[jt][r];
        }
        #pragma unroll
        for (int off = 1; off < 16; off <<= 1)
            s += __shfl_xor(s, off, 64);
        invl[r] = 1.0f / s;
    }

    // ---- PV over 4 key chunks ----
    f32x4 cacc[4] = {};
    bf16* Pw = &Ps[w * 16 * LD];
    for (int c = 0; c < 4; ++c) {
        __syncthreads();
        // stage V chunk transposed: Vt[d][j_local]
        {
            int row = tid >> 2, c0 = (tid & 3) * 16;  // row=j_local, c0=d start
            const bf16* src = Vg + (size_t)(c * 64 + row) * 64 + c0;
            bf16x8 v0 = *(const bf16x8*)(src);
            bf16x8 v1 = *(const bf16x8*)(src + 8);
            #pragma unroll
            for (int d = 0; d < 8; ++d) {
                Vt[(c0 + d) * LD + row]     = v0[d];
                Vt[(c0 + 8 + d) * LD + row] = v1[d];
            }
        }
        // write this wave's P chunk in A-layout: Pw[qrow 0..15][j_local 0..63]
        #pragma unroll
        for (int jtl = 0; jtl < 4; ++jtl) {
            int jt = c * 4 + jtl;
            #pragma unroll
            for (int r = 0; r < 4; ++r)
                Pw[(quad * 4 + r) * LD + jtl * 16 + l15] = (bf16)(p[jt][r] * invl[r]);
        }
        __syncthreads();
        bf16x8 pf0 = *(const bf16x8*)&Pw[l15 * LD + quad * 8];
        bf16x8 pf1 = *(const bf16x8*)&Pw[l15 * LD + 32 + quad * 8];
        #pragma unroll
        for (int dt = 0; dt < 4; ++dt) {
            bf16x8 vf0 = *(const bf16x8*)&Vt[(dt * 16 + l15) * LD + quad * 8];
            bf16x8 vf1 = *(const bf16x8*)&Vt[(dt * 16 + l15) * LD + 32 + quad * 8];
            cacc[dt] = MFMA_BF16(pf0, vf0, cacc[dt]);
            cacc[dt] = MFMA_BF16(pf1, vf1, cacc[dt]);
        }
    }

    // ---- store ctx [B, S, H*DH] bf16 ----
    const size_t obase = ((size_t)b * 256) * 768 + (size_t)h * 64;
    #pragma unroll
    for (int dt = 0; dt < 4; ++dt) {
        #pragma unroll
        for (int r = 0; r < 4; ++r) {
            int s = qt * 64 + w * 16 + quad * 4 + r;
            int d = dt * 16 + l15;
            ctx[obase + (size_t)s * 768 + d] = (bf16)cacc[dt][r];
        }
    }
}

extern "C" void kernel_launch(void* const* d_in, const int* in_sizes, int n_in,
                              void* d_out, int out_size, void* d_ws, size_t ws_size,
                              hipStream_t stream) {
    (void)in_sizes; (void)n_in; (void)out_size; (void)ws_size;
    const float* q     = (const float*)d_in[0];
    const float* k     = (const float*)d_in[1];
    const float* v     = (const float*)d_in[2];
    const float* Wq    = (const float*)d_in[3];
    const float* bq    = (const float*)d_in[4];
    const float* Wk    = (const float*)d_in[5];
    const float* bk    = (const float*)d_in[6];
    const float* Wv    = (const float*)d_in[7];
    const float* bv    = (const float*)d_in[8];
    const float* Wo    = (const float*)d_in[9];
    const float* bo    = (const float*)d_in[10];
    const float* table = (const float*)d_in[11];

    const size_t NE = (size_t)128 * 256 * 768;  // 25,165,824 elems per tensor
    bf16* qh  = (bf16*)d_ws;
    bf16* kh  = qh + NE;
    bf16* vh  = kh + NE;
    bf16* ctx = vh + NE;
    float* out = (float*)d_out;

    dim3 gblock(256);
    dim3 ggrid(256, 6);     // 32768/128 x 768/128
    gemm_proj<float, 0><<<ggrid, gblock, 0, stream>>>(q, Wq, bq, qh, nullptr);
    gemm_proj<float, 0><<<ggrid, gblock, 0, stream>>>(k, Wk, bk, kh, nullptr);
    gemm_proj<float, 0><<<ggrid, gblock, 0, stream>>>(v, Wv, bv, vh, nullptr);

    dim3 agrid(4, 12, 128);
    attn_kernel<<<agrid, gblock, 0, stream>>>(qh, kh, vh, table, ctx);

    gemm_proj<bf16, 1><<<ggrid, gblock, 0, stream>>>(ctx, Wo, bo, nullptr, out);
}

// Round 2
// 780.785 us; speedup vs baseline: 1.0399x; 1.0399x over previous
//
#include <hip/hip_runtime.h>

// ---------------------------------------------------------------------------
// AttentionRelativeBias: B=128, S=256, D=768, H=12, DH=64, window 8x8 (=64 tok)
// Pipeline: fused QKV GEMM (fp32 A via global_load_lds, cvt at frag read)
//           -> V transpose -> attention (DMA-staged tiles) -> out proj GEMM
// ws layout (201.3 MB, same footprint as round 1):
//   [qh 50.3MB][kh 50.3MB][vh 50.3MB -> reused as ctx][vt 50.3MB]
// ---------------------------------------------------------------------------

typedef __bf16 bf16;
typedef __bf16 bf16x8 __attribute__((ext_vector_type(8)));
typedef float  f32x4  __attribute__((ext_vector_type(4)));

#define MFMA_BF16(a, b, c) __builtin_amdgcn_mfma_f32_16x16x32_bf16((a), (b), (c), 0, 0, 0)

__device__ __forceinline__ void gld16(const void* g, void* l) {
    __builtin_amdgcn_global_load_lds(
        (const __attribute__((address_space(1))) void*)g,
        (__attribute__((address_space(3))) void*)l, 16, 0, 0);
}

__device__ __forceinline__ bf16x8 pack8(f32x4 lo, f32x4 hi) {
    bf16x8 r;
    r[0] = (bf16)lo[0]; r[1] = (bf16)lo[1]; r[2] = (bf16)lo[2]; r[3] = (bf16)lo[3];
    r[4] = (bf16)hi[0]; r[5] = (bf16)hi[1]; r[6] = (bf16)hi[2]; r[7] = (bf16)hi[3];
    return r;
}

// ---------------- fused QKV projection GEMM -------------------------------
// Y = X @ W^T + b ; X fp32 [32768,768], W fp32 [768,768]; out bf16 [B,H,S,DH]
__global__ __launch_bounds__(256)
void gemm_qkv(const float* __restrict__ q, const float* __restrict__ k,
              const float* __restrict__ v,
              const float* __restrict__ Wq, const float* __restrict__ Wk,
              const float* __restrict__ Wv,
              const float* __restrict__ bq, const float* __restrict__ bk,
              const float* __restrict__ bv, bf16* __restrict__ outbase)
{
    __shared__ float As[128 * 64];   // 32 KB, unpadded (global_load_lds layout)
    __shared__ bf16  Bs[128 * 64];   // 16 KB, unpadded

    const int z = blockIdx.z;
    const float* X    = (z == 0) ? q  : (z == 1) ? k  : v;
    const float* Wt   = (z == 0) ? Wq : (z == 1) ? Wk : Wv;
    const float* bias = (z == 0) ? bq : (z == 1) ? bk : bv;
    bf16* out = outbase + (size_t)z * 25165824;

    const int tid  = threadIdx.x;
    const int m0   = blockIdx.x * 128;
    const int n0   = blockIdx.y * 128;
    const int w    = tid >> 6;
    const int lane = tid & 63;
    const int quad = lane >> 4;
    const int l15  = lane & 15;
    const int wr   = (w >> 1) * 64;
    const int wc   = (w & 1) * 64;

    f32x4 acc[4][4] = {};

    for (int kt = 0; kt < 12; ++kt) {
        const int k0 = kt * 64;
        __syncthreads();
        // A tile 128x64 fp32 = 2048 x 16B granules, raw DMA to LDS
        #pragma unroll
        for (int p = 0; p < 8; ++p) {
            int g = p * 256 + tid;             // = (p*256 + w*64) + lane
            gld16(X + (size_t)(m0 + (g >> 4)) * 768 + k0 + (g & 15) * 4,
                  (char*)As + g * 16);
        }
        // B tile 128x64 -> bf16, manual (weights tiny, L2-resident)
        #pragma unroll
        for (int p = 0; p < 4; ++p) {
            int g = p * 256 + tid;
            const float* src = Wt + (size_t)(n0 + (g >> 3)) * 768 + k0 + (g & 7) * 8;
            f32x4 lo = *(const f32x4*)src;
            f32x4 hi = *(const f32x4*)(src + 4);
            *(bf16x8*)&Bs[g * 8] = pack8(lo, hi);
        }
        __syncthreads();
        #pragma unroll
        for (int kk = 0; kk < 2; ++kk) {
            bf16x8 af[4], bfr[4];
            #pragma unroll
            for (int mt = 0; mt < 4; ++mt) {
                const float* ap = &As[(wr + mt * 16 + l15) * 64 + kk * 32 + quad * 8];
                af[mt] = pack8(*(const f32x4*)ap, *(const f32x4*)(ap + 4));
            }
            #pragma unroll
            for (int nt = 0; nt < 4; ++nt)
                bfr[nt] = *(const bf16x8*)&Bs[(wc + nt * 16 + l15) * 64 + kk * 32 + quad * 8];
            #pragma unroll
            for (int mt = 0; mt < 4; ++mt)
                #pragma unroll
                for (int nt = 0; nt < 4; ++nt)
                    acc[mt][nt] = MFMA_BF16(af[mt], bfr[nt], acc[mt][nt]);
        }
    }

    #pragma unroll
    for (int mt = 0; mt < 4; ++mt) {
        #pragma unroll
        for (int nt = 0; nt < 4; ++nt) {
            int gn = n0 + wc + nt * 16 + l15;
            float bv = bias[gn];
            int h = gn >> 6, d = gn & 63;
            #pragma unroll
            for (int r = 0; r < 4; ++r) {
                int gm = m0 + wr + mt * 16 + quad * 4 + r;
                int b = gm >> 8, s = gm & 255;
                out[(((size_t)(b * 12 + h) << 8) + s) * 64 + d] = (bf16)(acc[mt][nt][r] + bv);
            }
        }
    }
}

// ---------------- output projection GEMM ----------------------------------
// out fp32 [32768,768] = ctx(bf16) @ Wo^T + bo
__global__ __launch_bounds__(256)
void gemm_out(const bf16* __restrict__ X, const float* __restrict__ Wt,
              const float* __restrict__ bias, float* __restrict__ out)
{
    __shared__ bf16 As[128 * 64];
    __shared__ bf16 Bs[128 * 64];

    const int tid  = threadIdx.x;
    const int m0   = blockIdx.x * 128;
    const int n0   = blockIdx.y * 128;
    const int w    = tid >> 6;
    const int lane = tid & 63;
    const int quad = lane >> 4;
    const int l15  = lane & 15;
    const int wr   = (w >> 1) * 64;
    const int wc   = (w & 1) * 64;

    f32x4 acc[4][4] = {};

    for (int kt = 0; kt < 12; ++kt) {
        const int k0 = kt * 64;
        __syncthreads();
        #pragma unroll
        for (int p = 0; p < 4; ++p) {
            int g = p * 256 + tid;
            gld16(X + (size_t)(m0 + (g >> 3)) * 768 + k0 + (g & 7) * 8,
                  (char*)As + g * 16);
        }
        #pragma unroll
        for (int p = 0; p < 4; ++p) {
            int g = p * 256 + tid;
            const float* src = Wt + (size_t)(n0 + (g >> 3)) * 768 + k0 + (g & 7) * 8;
            *(bf16x8*)&Bs[g * 8] = pack8(*(const f32x4*)src, *(const f32x4*)(src + 4));
        }
        __syncthreads();
        #pragma unroll
        for (int kk = 0; kk < 2; ++kk) {
            bf16x8 af[4], bfr[4];
            #pragma unroll
            for (int mt = 0; mt < 4; ++mt)
                af[mt] = *(const bf16x8*)&As[(wr + mt * 16 + l15) * 64 + kk * 32 + quad * 8];
            #pragma unroll
            for (int nt = 0; nt < 4; ++nt)
                bfr[nt] = *(const bf16x8*)&Bs[(wc + nt * 16 + l15) * 64 + kk * 32 + quad * 8];
            #pragma unroll
            for (int mt = 0; mt < 4; ++mt)
                #pragma unroll
                for (int nt = 0; nt < 4; ++nt)
                    acc[mt][nt] = MFMA_BF16(af[mt], bfr[nt], acc[mt][nt]);
        }
    }

    #pragma unroll
    for (int mt = 0; mt < 4; ++mt) {
        #pragma unroll
        for (int nt = 0; nt < 4; ++nt) {
            int gn = n0 + wc + nt * 16 + l15;
            float bv = bias[gn];
            #pragma unroll
            for (int r = 0; r < 4; ++r) {
                int gm = m0 + wr + mt * 16 + quad * 4 + r;
                out[(size_t)gm * 768 + gn] = acc[mt][nt][r] + bv;
            }
        }
    }
}

// ---------------- V transpose: [B,H,S,DH] -> [B,H,DH,S] -------------------
// LD=65 (odd) => both scalar LDS directions are <=2-way (free) conflicts.
__global__ __launch_bounds__(256)
void transpose_v(const bf16* __restrict__ vh, bf16* __restrict__ vt)
{
    __shared__ bf16 Ts[64 * 65];
    const int qt = blockIdx.x, h = blockIdx.y, b = blockIdx.z;
    const bf16* src = vh + ((size_t)(b * 12 + h) * 256 + qt * 64) * 64;
    bf16* dst = vt + (size_t)(b * 12 + h) * 64 * 256;

    const int tid = threadIdx.x;
    {
        int row = tid >> 2, c0 = (tid & 3) * 16;
        bf16x8 v0 = *(const bf16x8*)(src + row * 64 + c0);
        bf16x8 v1 = *(const bf16x8*)(src + row * 64 + c0 + 8);
        #pragma unroll
        for (int i = 0; i < 8; ++i) {
            Ts[row * 65 + c0 + i]     = v0[i];
            Ts[row * 65 + c0 + 8 + i] = v1[i];
        }
    }
    __syncthreads();
    {
        int d = tid >> 2, j0 = (tid & 3) * 16;
        bf16x8 o0, o1;
        #pragma unroll
        for (int i = 0; i < 8; ++i) {
            o0[i] = Ts[(j0 + i) * 65 + d];
            o1[i] = Ts[(j0 + 8 + i) * 65 + d];
        }
        *(bf16x8*)(dst + (size_t)d * 256 + qt * 64 + j0)     = o0;
        *(bf16x8*)(dst + (size_t)d * 256 + qt * 64 + j0 + 8) = o1;
    }
}

// ---------------- attention ------------------------------------------------
__global__ __launch_bounds__(256)
void attn_kernel(const bf16* __restrict__ qh, const bf16* __restrict__ kh,
                 const bf16* __restrict__ vt, const float* __restrict__ table,
                 bf16* __restrict__ ctx)
{
    __shared__ bf16 Qs[64 * 64];       // 8 KB, DMA-staged, unpadded
    __shared__ bf16 Ks[64 * 64];       // 8 KB
    __shared__ bf16 Vs[64 * 64];       // 8 KB (V^T chunk: [d][j_local])
    __shared__ bf16 Ps[4 * 16 * 72];   // 9.2 KB (per-wave P, LD=72)
    __shared__ bf16 Bsh[64 * 68];      // 8.7 KB bias tile
    // total 42.5 KB -> 3 blocks/CU

    const int tid  = threadIdx.x;
    const int qt   = blockIdx.x;
    const int h    = blockIdx.y;
    const int b    = blockIdx.z;
    const int w    = tid >> 6;
    const int lane = tid & 63;
    const int quad = lane >> 4;
    const int l15  = lane & 15;

    const size_t bh = (size_t)(b * 12 + h) * 256 * 64;
    const bf16* Qg  = qh + bh + (size_t)qt * 64 * 64;
    const bf16* Kg  = kh + bh;
    const bf16* Vtg = vt + bh;   // [64][256]

    // stage Q (DMA) + build bias tile
    #pragma unroll
    for (int p = 0; p < 2; ++p) {
        int g = p * 256 + tid;
        gld16(Qg + (size_t)(g >> 3) * 64 + (g & 7) * 8, (char*)Qs + g * 16);
    }
    {
        int i = tid >> 2, j0 = (tid & 3) * 16;
        int ai = i >> 3, aj = i & 7;
        #pragma unroll
        for (int jj = 0; jj < 16; ++jj) {
            int j = j0 + jj;
            int idx = (ai - (j >> 3) + 7) * 15 + (aj - (j & 7) + 7);
            Bsh[i * 68 + j] = (bf16)table[idx * 12 + h];
        }
    }

    // ---- QK^T over 4 key chunks ----
    f32x4 sacc[16] = {};
    bf16x8 qf0, qf1;
    for (int c = 0; c < 4; ++c) {
        __syncthreads();
        #pragma unroll
        for (int p = 0; p < 2; ++p) {
            int g = p * 256 + tid;
            gld16(Kg + (size_t)(c * 64 + (g >> 3)) * 64 + (g & 7) * 8, (char*)Ks + g * 16);
        }
        __syncthreads();
        if (c == 0) {
            qf0 = *(const bf16x8*)&Qs[(w * 16 + l15) * 64 + quad * 8];
            qf1 = *(const bf16x8*)&Qs[(w * 16 + l15) * 64 + 32 + quad * 8];
        }
        #pragma unroll
        for (int jtl = 0; jtl < 4; ++jtl) {
            bf16x8 kf0 = *(const bf16x8*)&Ks[(jtl * 16 + l15) * 64 + quad * 8];
            bf16x8 kf1 = *(const bf16x8*)&Ks[(jtl * 16 + l15) * 64 + 32 + quad * 8];
            sacc[c * 4 + jtl] = MFMA_BF16(qf0, kf0, sacc[c * 4 + jtl]);
            sacc[c * 4 + jtl] = MFMA_BF16(qf1, kf1, sacc[c * 4 + jtl]);
        }
    }

    // ---- softmax ----
    const int browbase = w * 16 + quad * 4;
    float p[16][4];
    #pragma unroll
    for (int jt = 0; jt < 16; ++jt) {
        int jcol = ((jt * 16) & 63) + l15;
        #pragma unroll
        for (int r = 0; r < 4; ++r)
            p[jt][r] = sacc[jt][r] * 0.125f + (float)Bsh[(browbase + r) * 68 + jcol];
    }
    float invl[4];
    #pragma unroll
    for (int r = 0; r < 4; ++r) {
        float m = p[0][r];
        #pragma unroll
        for (int jt = 1; jt < 16; ++jt) m = fmaxf(m, p[jt][r]);
        #pragma unroll
        for (int off = 1; off < 16; off <<= 1)
            m = fmaxf(m, __shfl_xor(m, off, 64));
        float s = 0.f;
        #pragma unroll
        for (int jt = 0; jt < 16; ++jt) {
            p[jt][r] = __expf(p[jt][r] - m);
            s += p[jt][r];
        }
        #pragma unroll
        for (int off = 1; off < 16; off <<= 1)
            s += __shfl_xor(s, off, 64);
        invl[r] = 1.0f / s;
    }

    // ---- PV over 4 key chunks ----
    f32x4 cacc[4] = {};
    bf16* Pw = &Ps[w * 16 * 72];
    for (int c = 0; c < 4; ++c) {
        __syncthreads();
        #pragma unroll
        for (int pp = 0; pp < 2; ++pp) {
            int g = pp * 256 + tid;   // row = d, col chunk within [c*64, c*64+64)
            gld16(Vtg + (size_t)(g >> 3) * 256 + c * 64 + (g & 7) * 8, (char*)Vs + g * 16);
        }
        #pragma unroll
        for (int jtl = 0; jtl < 4; ++jtl) {
            int jt = c * 4 + jtl;
            #pragma unroll
            for (int r = 0; r < 4; ++r)
                Pw[(quad * 4 + r) * 72 + jtl * 16 + l15] = (bf16)(p[jt][r] * invl[r]);
        }
        __syncthreads();
        bf16x8 pf0 = *(const bf16x8*)&Pw[l15 * 72 + quad * 8];
        bf16x8 pf1 = *(const bf16x8*)&Pw[l15 * 72 + 32 + quad * 8];
        #pragma unroll
        for (int dt = 0; dt < 4; ++dt) {
            bf16x8 vf0 = *(const bf16x8*)&Vs[(dt * 16 + l15) * 64 + quad * 8];
            bf16x8 vf1 = *(const bf16x8*)&Vs[(dt * 16 + l15) * 64 + 32 + quad * 8];
            cacc[dt] = MFMA_BF16(pf0, vf0, cacc[dt]);
            cacc[dt] = MFMA_BF16(pf1, vf1, cacc[dt]);
        }
    }

    // ---- store ctx [B, S, 768] bf16 ----
    const size_t obase = ((size_t)b * 256) * 768 + (size_t)h * 64;
    #pragma unroll
    for (int dt = 0; dt < 4; ++dt) {
        #pragma unroll
        for (int r = 0; r < 4; ++r) {
            int s = qt * 64 + w * 16 + quad * 4 + r;
            int d = dt * 16 + l15;
            ctx[obase + (size_t)s * 768 + d] = (bf16)cacc[dt][r];
        }
    }
}

extern "C" void kernel_launch(void* const* d_in, const int* in_sizes, int n_in,
                              void* d_out, int out_size, void* d_ws, size_t ws_size,
                              hipStream_t stream) {
    (void)in_sizes; (void)n_in; (void)out_size; (void)ws_size;
    const float* q     = (const float*)d_in[0];
    const float* k     = (const float*)d_in[1];
    const float* v     = (const float*)d_in[2];
    const float* Wq    = (const float*)d_in[3];
    const float* bq    = (const float*)d_in[4];
    const float* Wk    = (const float*)d_in[5];
    const float* bk    = (const float*)d_in[6];
    const float* Wv    = (const float*)d_in[7];
    const float* bv    = (const float*)d_in[8];
    const float* Wo    = (const float*)d_in[9];
    const float* bo    = (const float*)d_in[10];
    const float* table = (const float*)d_in[11];

    const size_t NE = (size_t)128 * 256 * 768;
    bf16* qh  = (bf16*)d_ws;
    bf16* kh  = qh + NE;
    bf16* vh  = kh + NE;        // reused as ctx after transpose_v consumes it
    bf16* vt  = vh + NE;
    bf16* ctx = vh;
    float* out = (float*)d_out;

    dim3 blk(256);
    gemm_qkv<<<dim3(256, 6, 3), blk, 0, stream>>>(q, k, v, Wq, Wk, Wv, bq, bk, bv, qh);
    transpose_v<<<dim3(4, 12, 128), blk, 0, stream>>>(vh, vt);
    attn_kernel<<<dim3(4, 12, 128), blk, 0, stream>>>(qh, kh, vt, table, ctx);
    gemm_out<<<dim3(256, 6), blk, 0, stream>>>(ctx, Wo, bo, out);
}